// Round 5
// baseline (7764.551 us; speedup 1.0000x reference)
//
#include <hip/hip_runtime.h>
#include <cstdint>

typedef short bf16x8 __attribute__((ext_vector_type(8)));
typedef float f32x4  __attribute__((ext_vector_type(4)));
typedef unsigned u32x4 __attribute__((ext_vector_type(4)));

constexpr int Bn = 16, Tn = 2048, Dn = 512, Hn = 512;
constexpr int NWG = 16;        // j-slice workgroups (32 h-columns each)
constexpr int JWG = 32;
constexpr int NTH = 512;       // 8 waves: (kw = wv&3) x (jw = wv>>2)

__device__ __forceinline__ unsigned short f2bf(float f) {
  union { float f; unsigned u; } v; v.f = f;
  unsigned r = v.u + 0x7FFFu + ((v.u >> 16) & 1u);   // RNE
  return (unsigned short)(r >> 16);
}

__global__ __launch_bounds__(NTH, 2) void gru_scan(
    const float* __restrict__ x, const int* __restrict__ start,
    const float* __restrict__ w_ih, const float* __restrict__ w_hh,
    const float* __restrict__ b_ih, const float* __restrict__ b_hh,
    float* __restrict__ out, unsigned* __restrict__ ring)   // u32 view of bf16 pairs
{
  const int tid  = threadIdx.x;
  const int lane = tid & 63;
  const int wv   = tid >> 6;
  const int kw   = wv & 3;           // K-slice 128*kw
  const int jw   = wv >> 2;          // 16-col half within WG
  const int arow = lane & 15;        // A row (batch) / B col index
  const int koff = (lane >> 4) * 8;
  const int j0w  = blockIdx.x * JWG + jw * 16;
  const int kb   = kw * 128;

  // ---- persistent weight B-fragments in registers (bf16) ----
  bf16x8 whf[3][4], wif[3][4];
  #pragma unroll
  for (int g = 0; g < 3; ++g) {
    const int grow = g * Hn + j0w + arow;
    #pragma unroll
    for (int s = 0; s < 4; ++s) {
      const int kk = kb + s * 32 + koff;
      const float* ph = w_hh + (size_t)grow * Dn + kk;
      const float* pi = w_ih + (size_t)grow * Dn + kk;
      bf16x8 a, b;
      #pragma unroll
      for (int i = 0; i < 8; ++i) { a[i] = (short)f2bf(ph[i]); b[i] = (short)f2bf(pi[i]); }
      whf[g][s] = a; wif[g][s] = b;
    }
  }

  // ---- per-thread epilogue mapping: tid -> (batch bq, col jj) ----
  const int bq = tid >> 5;
  const int jj = tid & 31;
  const int jg = blockIdx.x * JWG + jj;
  const float bias_r  = b_ih[jg]          + b_hh[jg];
  const float bias_z  = b_ih[Hn + jg]     + b_hh[Hn + jg];
  const float bias_nx = b_ih[2 * Hn + jg];
  const float bias_nh = b_hh[2 * Hn + jg];
  const int   start_g = start[bq];
  const int   start_a = start[arow];
  const int   jr      = jj ^ (((bq >> 2) & 1) << 4);   // swizzled reduce-read col

  float h_own = 0.f;
  float po0 = 0.f, po1 = 0.f;                          // delayed out-stores (prev step)
  __shared__ float red[2][4][4][16][32];               // [parity][gate][kw][batch][col]

  const float* xrow   = x + (size_t)arow * Tn * Dn + kb + koff;
  const float* xres_p = x + (size_t)bq   * Tn * Dn + jg;

  // two named prefetch sets (t even / t odd), refilled for t+2 post-poll
  f32x4 xa0[4][2], xa1[4][2]; float xr0, xr1;
  #pragma unroll
  for (int s = 0; s < 4; ++s) {
    xa0[s][0] = *(const f32x4*)(xrow + s * 32);
    xa0[s][1] = *(const f32x4*)(xrow + s * 32 + 4);
    xa1[s][0] = *(const f32x4*)(xrow + (size_t)Dn + s * 32);
    xa1[s][1] = *(const f32x4*)(xrow + (size_t)Dn + s * 32 + 4);
  }
  xr0 = xres_p[0]; xr1 = xres_p[Dn];

  auto step = [&](int t, f32x4 (&xa)[4][2], float& xr) {
    const bool have_h = (t > 0);
    const unsigned* hp =
        ring + (size_t)(t & 1) * (Bn * Hn / 2) + ((arow * Hn + kb + koff) >> 1);
    u32x4 a0, a1, a2, a3;
    // ---- pre-issue poll loads: first LLC RT hides under phase A ----
    if (have_h) {
      asm volatile("global_load_dwordx4 %0, %1, off sc0 sc1" : "=v"(a0) : "v"(hp)      : "memory");
      asm volatile("global_load_dwordx4 %0, %1, off sc0 sc1" : "=v"(a1) : "v"(hp + 16) : "memory");
      asm volatile("global_load_dwordx4 %0, %1, off sc0 sc1" : "=v"(a2) : "v"(hp + 32) : "memory");
      asm volatile("global_load_dwordx4 %0, %1, off sc0 sc1" : "=v"(a3) : "v"(hp + 48) : "memory");
    }

    // ---- phase A: convert x(t), input-projection MFMAs (no VM ops) ----
    const float xres = xr;
    bf16x8 xf[4];
    #pragma unroll
    for (int s = 0; s < 4; ++s) {
      unsigned d0, d1, d2, d3;
      asm("v_cvt_pk_bf16_f32 %0, %1, %2" : "=v"(d0) : "v"(xa[s][0][0]), "v"(xa[s][0][1]));
      asm("v_cvt_pk_bf16_f32 %0, %1, %2" : "=v"(d1) : "v"(xa[s][0][2]), "v"(xa[s][0][3]));
      asm("v_cvt_pk_bf16_f32 %0, %1, %2" : "=v"(d2) : "v"(xa[s][1][0]), "v"(xa[s][1][1]));
      asm("v_cvt_pk_bf16_f32 %0, %1, %2" : "=v"(d3) : "v"(xa[s][1][2]), "v"(xa[s][1][3]));
      union { u32x4 u; bf16x8 v; } xu;
      xu.u[0] = d0; xu.u[1] = d1; xu.u[2] = d2; xu.u[3] = d3;
      xf[s] = xu.v;
    }
    f32x4 ar = {0,0,0,0}, az = {0,0,0,0}, anx = {0,0,0,0}, anh = {0,0,0,0};
    #pragma unroll
    for (int s = 0; s < 4; ++s) {
      ar  = __builtin_amdgcn_mfma_f32_16x16x32_bf16(xf[s], wif[0][s], ar,  0, 0, 0);
      az  = __builtin_amdgcn_mfma_f32_16x16x32_bf16(xf[s], wif[1][s], az,  0, 0, 0);
      anx = __builtin_amdgcn_mfma_f32_16x16x32_bf16(xf[s], wif[2][s], anx, 0, 0, 0);
    }

    // ---- phase B: validate (parity tags in bf16 LSBs) ----
    if (have_h) {
      const unsigned pexp = (unsigned)((t >> 1) & 1);
      for (;;) {
        asm volatile("s_waitcnt vmcnt(0)" ::: "memory");
        __builtin_amdgcn_sched_barrier(0);
        const unsigned andv = a0[0] & a0[1] & a0[2] & a0[3] & a1[0] & a1[1] & a1[2] & a1[3]
                            & a2[0] & a2[1] & a2[2] & a2[3] & a3[0] & a3[1] & a3[2] & a3[3];
        const unsigned orv  = a0[0] | a0[1] | a0[2] | a0[3] | a1[0] | a1[1] | a1[2] | a1[3]
                            | a2[0] | a2[1] | a2[2] | a2[3] | a3[0] | a3[1] | a3[2] | a3[3];
        const int ok = pexp ? ((andv & 0x00010001u) == 0x00010001u)
                            : ((orv  & 0x00010001u) == 0u);
        if (__all(ok)) break;
        asm volatile("global_load_dwordx4 %0, %1, off sc0 sc1" : "=v"(a0) : "v"(hp)      : "memory");
        asm volatile("global_load_dwordx4 %0, %1, off sc0 sc1" : "=v"(a1) : "v"(hp + 16) : "memory");
        asm volatile("global_load_dwordx4 %0, %1, off sc0 sc1" : "=v"(a2) : "v"(hp + 32) : "memory");
        asm volatile("global_load_dwordx4 %0, %1, off sc0 sc1" : "=v"(a3) : "v"(hp + 48) : "memory");
      }
      __builtin_amdgcn_sched_barrier(0);
      // delayed out-stores for step t-1: full step to retire before next poll
      const size_t poo = ((size_t)bq * Tn + (t - 1)) * Hn + jg;
      out[poo] = po0;
      out[(size_t)Bn * Tn * Hn + poo] = po1;
    }

    // ---- x refill for t+2 (retires during compute+publish+next phase A) ----
    {
      const int tf = (t + 2 < Tn) ? (t + 2) : (Tn - 1);
      const float* xt = xrow + (size_t)tf * Dn;
      #pragma unroll
      for (int s = 0; s < 4; ++s) {
        xa[s][0] = *(const f32x4*)(xt + s * 32);
        xa[s][1] = *(const f32x4*)(xt + s * 32 + 4);
      }
      xr = xres_p[(size_t)tf * Dn];
    }

    // ---- phase C: hidden-projection MFMAs (mask at A-operand) ----
    if (have_h) {
      const bool am = (start_a < t);
      union { u32x4 u; bf16x8 v; } c0, c1, c2, c3;
      const u32x4 zz = {0, 0, 0, 0};
      c0.u = am ? a0 : zz; c1.u = am ? a1 : zz; c2.u = am ? a2 : zz; c3.u = am ? a3 : zz;
      ar  = __builtin_amdgcn_mfma_f32_16x16x32_bf16(c0.v, whf[0][0], ar,  0, 0, 0);
      az  = __builtin_amdgcn_mfma_f32_16x16x32_bf16(c0.v, whf[1][0], az,  0, 0, 0);
      anh = __builtin_amdgcn_mfma_f32_16x16x32_bf16(c0.v, whf[2][0], anh, 0, 0, 0);
      ar  = __builtin_amdgcn_mfma_f32_16x16x32_bf16(c1.v, whf[0][1], ar,  0, 0, 0);
      az  = __builtin_amdgcn_mfma_f32_16x16x32_bf16(c1.v, whf[1][1], az,  0, 0, 0);
      anh = __builtin_amdgcn_mfma_f32_16x16x32_bf16(c1.v, whf[2][1], anh, 0, 0, 0);
      ar  = __builtin_amdgcn_mfma_f32_16x16x32_bf16(c2.v, whf[0][2], ar,  0, 0, 0);
      az  = __builtin_amdgcn_mfma_f32_16x16x32_bf16(c2.v, whf[1][2], az,  0, 0, 0);
      anh = __builtin_amdgcn_mfma_f32_16x16x32_bf16(c2.v, whf[2][2], anh, 0, 0, 0);
      ar  = __builtin_amdgcn_mfma_f32_16x16x32_bf16(c3.v, whf[0][3], ar,  0, 0, 0);
      az  = __builtin_amdgcn_mfma_f32_16x16x32_bf16(c3.v, whf[1][3], az,  0, 0, 0);
      anh = __builtin_amdgcn_mfma_f32_16x16x32_bf16(c3.v, whf[2][3], anh, 0, 0, 0);
    }

    // ---- phase D: reduce (parity-double-buffered, swizzled) + gates ----
    const int par = t & 1;
    #pragma unroll
    for (int i = 0; i < 4; ++i) {
      const int r_ = (lane >> 4) * 4 + i;
      const int c_ = (jw * 16 + (lane & 15)) ^ (((lane >> 4) & 1) << 4);  // 2-way max
      red[par][0][kw][r_][c_] = ar[i];
      red[par][1][kw][r_][c_] = az[i];
      red[par][2][kw][r_][c_] = anx[i];
      red[par][3][kw][r_][c_] = anh[i];
    }
    __syncthreads();
    float sr = bias_r, sz = bias_z, snx = bias_nx, snh = bias_nh;
    #pragma unroll
    for (int k2 = 0; k2 < 4; ++k2) {
      sr  += red[par][0][k2][bq][jr];
      sz  += red[par][1][k2][bq][jr];
      snx += red[par][2][k2][bq][jr];
      snh += red[par][3][k2][bq][jr];
    }
    const float r  = 1.f / (1.f + __expf(-sr));
    const float z  = 1.f / (1.f + __expf(-sz));
    const float ea = __expf(2.f * (snx + r * snh));
    const float n  = 1.f - 2.f / (ea + 1.f);             // NaN-safe tanh
    const float hm = (start_g < t) ? h_own : 0.f;
    const float hn = (1.f - z) * n + z * hm;
    h_own = hn;

    // ---- phase E: direct publish (gen t+1 tag in bf16 LSB, dword atoms) ----
    const unsigned short ptag = (unsigned short)(((t + 1) >> 1) & 1);
    const unsigned short hb16 = (unsigned short)((f2bf(hn) & 0xFFFEu) | ptag);
    const unsigned partner = (unsigned)__shfl_xor((int)(unsigned)hb16, 1, 64) & 0xFFFFu;
    if (!(jj & 1)) {
      const unsigned packed = ((unsigned)hb16) | (partner << 16);
      unsigned* dst = ring + (size_t)((t + 1) & 1) * (Bn * Hn / 2) + ((bq * Hn + jg) >> 1);
      asm volatile("global_store_dword %0, %1, off sc0 sc1" :: "v"(dst), "v"(packed) : "memory");
    }

    // stash outputs for delayed store at step t+1
    po0 = xres + hn;
    po1 = hn;
  };

  #pragma unroll 1
  for (int t = 0; t < Tn; t += 2) {
    step(t,     xa0, xr0);
    step(t + 1, xa1, xr1);
  }
  // final outputs (step Tn-1)
  {
    const size_t poo = ((size_t)bq * Tn + (Tn - 1)) * Hn + jg;
    out[poo] = po0;
    out[(size_t)Bn * Tn * Hn + poo] = po1;
  }
}

extern "C" void kernel_launch(void* const* d_in, const int* in_sizes, int n_in,
                              void* d_out, int out_size, void* d_ws, size_t ws_size,
                              hipStream_t stream) {
  const float* x     = (const float*)d_in[0];
  const int*   start = (const int*)d_in[1];
  const float* w_ih  = (const float*)d_in[2];
  const float* w_hh  = (const float*)d_in[3];
  const float* b_ih  = (const float*)d_in[4];
  const float* b_hh  = (const float*)d_in[5];
  float* out = (float*)d_out;

  unsigned* ring = (unsigned*)d_ws;   // [2][16][512] bf16 ping-pong, u32 view

  // Parity init: buf0 bytes 0x00 (tag 0; first read t=2 expects 1), buf1 bytes
  // 0x01 (tag 1; first read t=1 expects 0). Stale replay gens (2047 tag1 in
  // buf1, 2048 tag0 in buf0) are overwritten by these memsets. Graph-safe.
  hipMemsetAsync(d_ws, 0x00, 16384, stream);
  hipMemsetAsync((char*)d_ws + 16384, 0x01, 16384, stream);
  hipLaunchKernelGGL(gru_scan, dim3(NWG), dim3(NTH), 0, stream,
                     x, start, w_ih, w_hh, b_ih, b_hh, out, ring);
}

// Round 6
// 6657.629 us; speedup vs baseline: 1.1663x; 1.1663x over previous
//
#include <hip/hip_runtime.h>
#include <cstdint>

typedef short bf16x8 __attribute__((ext_vector_type(8)));
typedef float f32x4  __attribute__((ext_vector_type(4)));
typedef unsigned u32x4 __attribute__((ext_vector_type(4)));

constexpr int Bn = 16, Tn = 2048, Dn = 512, Hn = 512;
constexpr int NWG = 16, JWG = 32, NTH = 512;
constexpr int TC1 = 16;   // timesteps per pass-1 workgroup

#define MFMA16(a, b, c) __builtin_amdgcn_mfma_f32_16x16x32_bf16((a), (b), (c), 0, 0, 0)

__device__ __forceinline__ unsigned short f2bf(float f) {
  union { float f; unsigned u; } v; v.f = f;
  unsigned r = v.u + 0x7FFFu + ((v.u >> 16) & 1u);   // RNE
  return (unsigned short)(r >> 16);
}
__device__ __forceinline__ float lo2f(unsigned u) { union { unsigned u; float f; } v; v.u = u << 16;        return v.f; }
__device__ __forceinline__ float hi2f(unsigned u) { union { unsigned u; float f; } v; v.u = u & 0xFFFF0000u; return v.f; }
__device__ __forceinline__ float asf(unsigned u)  { union { unsigned u; float f; } v; v.u = u; return v.f; }
__device__ __forceinline__ unsigned asu(float f)  { union { float f; unsigned u; } v; v.f = f; return v.u; }

// ============ pass 1: x_proj = x @ w_ih^T + b_ih (+ b_hh for r,z), bf16 ============
__global__ __launch_bounds__(NTH, 2) void xproj_pass(
    const float* __restrict__ x, const float* __restrict__ w_ih,
    const float* __restrict__ b_ih, const float* __restrict__ b_hh,
    unsigned* __restrict__ xrz, unsigned short* __restrict__ xnb)
{
  const int tid = threadIdx.x, lane = tid & 63, wv = tid >> 6;
  const int kw = wv & 3, jw = wv >> 2;
  const int arow = lane & 15, koff = (lane >> 4) * 8;
  const int wg = blockIdx.x, t0 = blockIdx.y * TC1;
  const int kb = kw * 128;

  bf16x8 wif[3][4];
  #pragma unroll
  for (int g = 0; g < 3; ++g) {
    const int grow = g * Hn + wg * JWG + jw * 16 + arow;
    #pragma unroll
    for (int s = 0; s < 4; ++s) {
      const float* pi = w_ih + (size_t)grow * Dn + kb + s * 32 + koff;
      bf16x8 b;
      #pragma unroll
      for (int i = 0; i < 8; ++i) b[i] = (short)f2bf(pi[i]);
      wif[g][s] = b;
    }
  }
  const int bq = tid >> 5, jj = tid & 31, jg = wg * JWG + jj;
  const float br = b_ih[jg]          + b_hh[jg];
  const float bz = b_ih[Hn + jg]     + b_hh[Hn + jg];
  const float bn = b_ih[2 * Hn + jg];                  // b_hh[n] stays in pass 2

  __shared__ float red[3][4][16][32];
  const float* xrow = x + (size_t)arow * Tn * Dn + kb + koff;

  for (int tt = 0; tt < TC1; ++tt) {
    const int t = t0 + tt;
    const float* xt = xrow + (size_t)t * Dn;
    f32x4 xa[4][2];
    #pragma unroll
    for (int s = 0; s < 4; ++s) {
      xa[s][0] = *(const f32x4*)(xt + s * 32);
      xa[s][1] = *(const f32x4*)(xt + s * 32 + 4);
    }
    bf16x8 xf[4];
    #pragma unroll
    for (int s = 0; s < 4; ++s) {
      unsigned d0, d1, d2, d3;
      asm("v_cvt_pk_bf16_f32 %0, %1, %2" : "=v"(d0) : "v"(xa[s][0][0]), "v"(xa[s][0][1]));
      asm("v_cvt_pk_bf16_f32 %0, %1, %2" : "=v"(d1) : "v"(xa[s][0][2]), "v"(xa[s][0][3]));
      asm("v_cvt_pk_bf16_f32 %0, %1, %2" : "=v"(d2) : "v"(xa[s][1][0]), "v"(xa[s][1][1]));
      asm("v_cvt_pk_bf16_f32 %0, %1, %2" : "=v"(d3) : "v"(xa[s][1][2]), "v"(xa[s][1][3]));
      union { u32x4 u; bf16x8 v; } xu;
      xu.u[0] = d0; xu.u[1] = d1; xu.u[2] = d2; xu.u[3] = d3;
      xf[s] = xu.v;
    }
    f32x4 ar = {0,0,0,0}, az = {0,0,0,0}, an = {0,0,0,0};
    #pragma unroll
    for (int s = 0; s < 4; ++s) {
      ar = MFMA16(xf[s], wif[0][s], ar);
      az = MFMA16(xf[s], wif[1][s], az);
      an = MFMA16(xf[s], wif[2][s], an);
    }
    #pragma unroll
    for (int i = 0; i < 4; ++i) {
      const int r_ = (lane >> 4) * 4 + i, c_ = jw * 16 + (lane & 15);
      red[0][kw][r_][c_] = ar[i];
      red[1][kw][r_][c_] = az[i];
      red[2][kw][r_][c_] = an[i];
    }
    __syncthreads();
    float sr = br, sz = bz, sn = bn;
    #pragma unroll
    for (int k2 = 0; k2 < 4; ++k2) {
      sr += red[0][k2][bq][jj];
      sz += red[1][k2][bq][jj];
      sn += red[2][k2][bq][jj];
    }
    unsigned rz;
    asm("v_cvt_pk_bf16_f32 %0, %1, %2" : "=v"(rz) : "v"(sr), "v"(sz));
    const size_t o = (size_t)(wg * Tn + t) * 512 + tid;
    xrz[o] = rz;
    xnb[o] = f2bf(sn);
    __syncthreads();
  }
}

// ============ pass 2: the recurrence (16 WGs, parity-tagged LLC ring) ============
template<bool XP>
__global__ __launch_bounds__(NTH, 2) void gru_scan(
    const float* __restrict__ x, const int* __restrict__ start,
    const float* __restrict__ w_ih, const float* __restrict__ w_hh,
    const float* __restrict__ b_ih, const float* __restrict__ b_hh,
    float* __restrict__ out, unsigned* __restrict__ ring,
    const unsigned* __restrict__ xrz, const unsigned short* __restrict__ xnb)
{
  const int tid = threadIdx.x, lane = tid & 63, wv = tid >> 6;
  const int kw = wv & 3, jw = wv >> 2;
  const int arow = lane & 15, koff = (lane >> 4) * 8;
  const int kb = kw * 128;
  constexpr int NG = XP ? 3 : 4;

  bf16x8 whf[3][4], wif[3][4];
  #pragma unroll
  for (int g = 0; g < 3; ++g) {
    const int grow = g * Hn + blockIdx.x * JWG + jw * 16 + arow;
    #pragma unroll
    for (int s = 0; s < 4; ++s) {
      const float* ph = w_hh + (size_t)grow * Dn + kb + s * 32 + koff;
      bf16x8 a;
      #pragma unroll
      for (int i = 0; i < 8; ++i) a[i] = (short)f2bf(ph[i]);
      whf[g][s] = a;
      if constexpr (!XP) {
        const float* pi = w_ih + (size_t)grow * Dn + kb + s * 32 + koff;
        bf16x8 b;
        #pragma unroll
        for (int i = 0; i < 8; ++i) b[i] = (short)f2bf(pi[i]);
        wif[g][s] = b;
      }
    }
  }

  const int bq = tid >> 5, jj = tid & 31, jg = blockIdx.x * JWG + jj;
  const float bias_nh = b_hh[2 * Hn + jg];
  float bias_r = 0.f, bias_z = 0.f, bias_nx = 0.f;
  if constexpr (!XP) {
    bias_r  = b_ih[jg]      + b_hh[jg];
    bias_z  = b_ih[Hn + jg] + b_hh[Hn + jg];
    bias_nx = b_ih[2 * Hn + jg];
  }
  const int start_g = start[bq];
  const int start_a = start[arow];
  const int jr = jj ^ (((bq >> 2) & 1) << 4);          // swizzled reduce-read col

  float h_own = 0.f;
  unsigned po0u = 0u, po1u = 0u;                        // delayed out stores
  __shared__ float red[2][NG][4][16][32];               // parity double-buffered

  const float*          xres_p = x   + (size_t)bq * Tn * Dn + jg;
  const unsigned*       xrz_p  = xrz + (size_t)blockIdx.x * Tn * 512 + tid;
  const unsigned short* xn_p   = xnb + (size_t)blockIdx.x * Tn * 512 + tid;
  const float*          xrow   = x   + (size_t)arow * Tn * Dn + kb + koff;

  // prefetch state: 4 named sets (XP), or 2 named x-tile sets (!XP)
  unsigned prz0=0, prz1=0, prz2=0, prz3=0, pn0=0, pn1=0, pn2=0, pn3=0;
  unsigned pxr0=0, pxr1=0, pxr2=0, pxr3=0;
  f32x4 xa0[4][2], xa1[4][2]; float xr0 = 0.f, xr1 = 0.f;
  if constexpr (XP) {
    prz0 = xrz_p[0];   pn0 = xn_p[0];
    prz1 = xrz_p[512]; pn1 = xn_p[512];
    pxr0 = asu(xres_p[0]); pxr1 = asu(xres_p[Dn]);
  } else {
    #pragma unroll
    for (int s = 0; s < 4; ++s) {
      xa0[s][0] = *(const f32x4*)(xrow + s * 32);
      xa0[s][1] = *(const f32x4*)(xrow + s * 32 + 4);
      xa1[s][0] = *(const f32x4*)(xrow + (size_t)Dn + s * 32);
      xa1[s][1] = *(const f32x4*)(xrow + (size_t)Dn + s * 32 + 4);
    }
    xr0 = xres_p[0]; xr1 = xres_p[Dn];
  }

  auto step = [&](int t, unsigned& crz, unsigned& cn, unsigned& cxr,
                  unsigned& frz, unsigned& fn, unsigned& fxr,
                  f32x4 (&xa)[4][2], float& xr) {
    const bool hv = (t > 0);
    const float xres_t = XP ? asf(cxr) : xr;
    f32x4 ar = {0,0,0,0}, az = {0,0,0,0}, anx = {0,0,0,0}, anh = {0,0,0,0};

    // ---- (!XP) phase A: input projection from registers ----
    if constexpr (!XP) {
      bf16x8 xf[4];
      #pragma unroll
      for (int s = 0; s < 4; ++s) {
        unsigned d0, d1, d2, d3;
        asm("v_cvt_pk_bf16_f32 %0, %1, %2" : "=v"(d0) : "v"(xa[s][0][0]), "v"(xa[s][0][1]));
        asm("v_cvt_pk_bf16_f32 %0, %1, %2" : "=v"(d1) : "v"(xa[s][0][2]), "v"(xa[s][0][3]));
        asm("v_cvt_pk_bf16_f32 %0, %1, %2" : "=v"(d2) : "v"(xa[s][1][0]), "v"(xa[s][1][1]));
        asm("v_cvt_pk_bf16_f32 %0, %1, %2" : "=v"(d3) : "v"(xa[s][1][2]), "v"(xa[s][1][3]));
        union { u32x4 u; bf16x8 v; } xu;
        xu.u[0] = d0; xu.u[1] = d1; xu.u[2] = d2; xu.u[3] = d3;
        xf[s] = xu.v;
      }
      #pragma unroll
      for (int s = 0; s < 4; ++s) {
        ar  = MFMA16(xf[s], wif[0][s], ar);
        az  = MFMA16(xf[s], wif[1][s], az);
        anx = MFMA16(xf[s], wif[2][s], anx);
      }
    }

    // ---- vmcnt ledger (all asm): [pub 1][polls 4][pf 3][out 2] -> vmcnt(5) ----
    const unsigned* hp = ring + (size_t)(t & 1) * (Bn * Hn / 2) + ((arow * Hn + kb + koff) >> 1);
    u32x4 a0, a1, a2, a3;
    if (hv) {
      asm volatile("global_load_dwordx4 %0, %1, off sc0 sc1" : "=v"(a0) : "v"(hp)      : "memory");
      asm volatile("global_load_dwordx4 %0, %1, off sc0 sc1" : "=v"(a1) : "v"(hp + 16) : "memory");
      asm volatile("global_load_dwordx4 %0, %1, off sc0 sc1" : "=v"(a2) : "v"(hp + 32) : "memory");
      asm volatile("global_load_dwordx4 %0, %1, off sc0 sc1" : "=v"(a3) : "v"(hp + 48) : "memory");
    }
    if constexpr (XP) {   // prefetch t+2 into the far set (3 asm loads)
      const int tf = (t + 2 < Tn) ? t + 2 : Tn - 1;
      const unsigned*       p1 = xrz_p + (size_t)tf * 512;
      const unsigned short* p2 = xn_p  + (size_t)tf * 512;
      const float*          p3 = xres_p + (size_t)tf * Dn;
      asm volatile("global_load_dword  %0, %1, off" : "=v"(frz) : "v"(p1) : "memory");
      asm volatile("global_load_ushort %0, %1, off" : "=v"(fn)  : "v"(p2) : "memory");
      asm volatile("global_load_dword  %0, %1, off" : "=v"(fxr) : "v"(p3) : "memory");
    }
    if (hv) {             // delayed out stores for t-1 (2 asm stores)
      const size_t poo = ((size_t)bq * Tn + (t - 1)) * Hn + jg;
      const float* q0 = out + poo;
      const float* q1 = out + (size_t)Bn * Tn * Hn + poo;
      asm volatile("global_store_dword %0, %1, off" :: "v"(q0), "v"(po0u) : "memory");
      asm volatile("global_store_dword %0, %1, off" :: "v"(q1), "v"(po1u) : "memory");
    }

    // ---- validate (parity tags in bf16 LSBs) ----
    if (hv) {
      if constexpr (XP) { asm volatile("s_waitcnt vmcnt(5)" ::: "memory"); }
      else              { asm volatile("s_waitcnt vmcnt(0)" ::: "memory"); }
      __builtin_amdgcn_sched_barrier(0);
      const unsigned pexp = (unsigned)((t >> 1) & 1);
      for (;;) {
        const unsigned andv = a0[0] & a0[1] & a0[2] & a0[3] & a1[0] & a1[1] & a1[2] & a1[3]
                            & a2[0] & a2[1] & a2[2] & a2[3] & a3[0] & a3[1] & a3[2] & a3[3];
        const unsigned orv  = a0[0] | a0[1] | a0[2] | a0[3] | a1[0] | a1[1] | a1[2] | a1[3]
                            | a2[0] | a2[1] | a2[2] | a2[3] | a3[0] | a3[1] | a3[2] | a3[3];
        const int ok = pexp ? ((andv & 0x00010001u) == 0x00010001u)
                            : ((orv  & 0x00010001u) == 0u);
        if (__all(ok)) break;
        __builtin_amdgcn_s_sleep(1);
        asm volatile("global_load_dwordx4 %0, %1, off sc0 sc1" : "=v"(a0) : "v"(hp)      : "memory");
        asm volatile("global_load_dwordx4 %0, %1, off sc0 sc1" : "=v"(a1) : "v"(hp + 16) : "memory");
        asm volatile("global_load_dwordx4 %0, %1, off sc0 sc1" : "=v"(a2) : "v"(hp + 32) : "memory");
        asm volatile("global_load_dwordx4 %0, %1, off sc0 sc1" : "=v"(a3) : "v"(hp + 48) : "memory");
        asm volatile("s_waitcnt vmcnt(0)" ::: "memory");
        __builtin_amdgcn_sched_barrier(0);
      }
    }

    // ---- (!XP) x refill for t+2 ----
    if constexpr (!XP) {
      const int tf = (t + 2 < Tn) ? t + 2 : Tn - 1;
      const float* xt = xrow + (size_t)tf * Dn;
      #pragma unroll
      for (int s = 0; s < 4; ++s) {
        xa[s][0] = *(const f32x4*)(xt + s * 32);
        xa[s][1] = *(const f32x4*)(xt + s * 32 + 4);
      }
      xr = xres_p[(size_t)tf * Dn];
    }

    // ---- hidden projection MFMAs ----
    if (hv) {
      const bool am = (start_a < t);
      union { u32x4 u; bf16x8 v; } c0, c1, c2, c3;
      const u32x4 zz = {0, 0, 0, 0};
      c0.u = am ? a0 : zz; c1.u = am ? a1 : zz; c2.u = am ? a2 : zz; c3.u = am ? a3 : zz;
      ar  = MFMA16(c0.v, whf[0][0], ar);  az  = MFMA16(c0.v, whf[1][0], az);
      anh = MFMA16(c0.v, whf[2][0], anh);
      ar  = MFMA16(c1.v, whf[0][1], ar);  az  = MFMA16(c1.v, whf[1][1], az);
      anh = MFMA16(c1.v, whf[2][1], anh);
      ar  = MFMA16(c2.v, whf[0][2], ar);  az  = MFMA16(c2.v, whf[1][2], az);
      anh = MFMA16(c2.v, whf[2][2], anh);
      ar  = MFMA16(c3.v, whf[0][3], ar);  az  = MFMA16(c3.v, whf[1][3], az);
      anh = MFMA16(c3.v, whf[2][3], anh);
    }

    // ---- reduce (one barrier, parity double-buffered, swizzled) + gates ----
    const int par = t & 1;
    #pragma unroll
    for (int i = 0; i < 4; ++i) {
      const int r_ = (lane >> 4) * 4 + i;
      const int c_ = (jw * 16 + (lane & 15)) ^ (((lane >> 4) & 1) << 4);
      red[par][0][kw][r_][c_] = ar[i];
      red[par][1][kw][r_][c_] = az[i];
      if constexpr (XP) {
        red[par][2][kw][r_][c_] = anh[i];
      } else {
        red[par][2][kw][r_][c_] = anx[i];
        red[par][3][kw][r_][c_] = anh[i];
      }
    }
    __syncthreads();
    float sr, sz, snx, snh;
    if constexpr (XP) { sr = lo2f(crz); sz = hi2f(crz); snx = lo2f(cn); snh = bias_nh; }
    else              { sr = bias_r;    sz = bias_z;    snx = bias_nx;  snh = bias_nh; }
    #pragma unroll
    for (int k2 = 0; k2 < 4; ++k2) {
      sr += red[par][0][k2][bq][jr];
      sz += red[par][1][k2][bq][jr];
      if constexpr (XP) {
        snh += red[par][2][k2][bq][jr];
      } else {
        snx += red[par][2][k2][bq][jr];
        snh += red[par][3][k2][bq][jr];
      }
    }
    const float r  = 1.f / (1.f + __expf(-sr));
    const float z  = 1.f / (1.f + __expf(-sz));
    const float ea = __expf(2.f * (snx + r * snh));
    const float n  = 1.f - 2.f / (ea + 1.f);             // NaN-safe tanh
    const float hm = (start_g < t) ? h_own : 0.f;
    const float hn = (1.f - z) * n + z * hm;
    h_own = hn;

    // ---- per-wave publish (gen t+1 tag in bf16 LSB; no second barrier) ----
    const unsigned short ptag = (unsigned short)(((t + 1) >> 1) & 1);
    const unsigned hb16 = (unsigned)((f2bf(hn) & 0xFFFEu) | ptag);
    const unsigned partner = (unsigned)__shfl_xor((int)hb16, 1, 64) & 0xFFFFu;
    if (!(jj & 1)) {
      const unsigned packed = hb16 | (partner << 16);
      unsigned* dst = ring + (size_t)((t + 1) & 1) * (Bn * Hn / 2) + ((bq * Hn + jg) >> 1);
      asm volatile("global_store_dword %0, %1, off sc0 sc1" :: "v"(dst), "v"(packed) : "memory");
    }

    po0u = asu(xres_t + hn);
    po1u = asu(hn);
  };

  #pragma unroll 1
  for (int t = 0; t < Tn; t += 4) {
    step(t + 0, prz0, pn0, pxr0, prz2, pn2, pxr2, xa0, xr0);
    step(t + 1, prz1, pn1, pxr1, prz3, pn3, pxr3, xa1, xr1);
    step(t + 2, prz2, pn2, pxr2, prz0, pn0, pxr0, xa0, xr0);
    step(t + 3, prz3, pn3, pxr3, prz1, pn1, pxr1, xa1, xr1);
  }
  {   // final outputs (t = Tn-1)
    const size_t poo = ((size_t)bq * Tn + (Tn - 1)) * Hn + jg;
    out[poo] = asf(po0u);
    out[(size_t)Bn * Tn * Hn + poo] = asf(po1u);
  }
}

extern "C" void kernel_launch(void* const* d_in, const int* in_sizes, int n_in,
                              void* d_out, int out_size, void* d_ws, size_t ws_size,
                              hipStream_t stream) {
  const float* x     = (const float*)d_in[0];
  const int*   start = (const int*)d_in[1];
  const float* w_ih  = (const float*)d_in[2];
  const float* w_hh  = (const float*)d_in[3];
  const float* b_ih  = (const float*)d_in[4];
  const float* b_hh  = (const float*)d_in[5];
  float* out = (float*)d_out;

  // ws: [0,32KB) parity ring | [64KB, +64MB) xrz bf16-pairs | then xn bf16
  unsigned* ring = (unsigned*)d_ws;
  const size_t xrz_off   = 65536;
  const size_t xrz_bytes = (size_t)NWG * Tn * 512 * 4;   // 64 MiB
  const size_t xn_bytes  = (size_t)NWG * Tn * 512 * 2;   // 32 MiB
  unsigned*       xrz = (unsigned*)((char*)d_ws + xrz_off);
  unsigned short* xnb = (unsigned short*)((char*)d_ws + xrz_off + xrz_bytes);
  const bool xp = ws_size >= xrz_off + xrz_bytes + xn_bytes;

  // ring parity init: buf0 LSB=0 (first read t=2 expects 1), buf1 LSB=1
  // (first read t=1 expects 0). Graph-capture-safe.
  hipMemsetAsync(d_ws, 0x00, 16384, stream);
  hipMemsetAsync((char*)d_ws + 16384, 0x01, 16384, stream);
  if (xp) {
    hipLaunchKernelGGL(xproj_pass, dim3(NWG, Tn / TC1), dim3(NTH), 0, stream,
                       x, w_ih, b_ih, b_hh, xrz, xnb);
    hipLaunchKernelGGL(gru_scan<true>, dim3(NWG), dim3(NTH), 0, stream,
                       x, start, w_ih, w_hh, b_ih, b_hh, out, ring, xrz, xnb);
  } else {
    hipLaunchKernelGGL(gru_scan<false>, dim3(NWG), dim3(NTH), 0, stream,
                       x, start, w_ih, w_hh, b_ih, b_hh, out, ring,
                       (const unsigned*)d_ws, (const unsigned short*)d_ws);
  }
}